// Round 1
// baseline (76.586 us; speedup 1.0000x reference)
//
#include <hip/hip_runtime.h>

// LocallyConnected2d: x(16,3,128,128) f32, W(61,61,64,3,8,8) f32, bias(64,61,61) f32
// out(16,1,488,488) f32 ; stride 2, kernel 8, no pad; pixel-shuffle r=8 epilogue.
//
// One block per output position hw (3721 blocks, 256 threads).
// - Stage x patch for all 16 batches in LDS (16 x 192 f32 = 12 KB).
// - Thread (oc = wave*16 + lane&15, kh = lane>>4) accumulates acc[16] over its
//   K/4 = 48 slice of the 192-long dot product, reading W directly from global
//   (each W element read by exactly one thread -> 183 MB HBM, the roofline term).
// - __shfl_xor(16/32) butterfly combines the 4 kh partials; kh-groups split the
//   16 batch stores (4 each).

namespace {
constexpr int NHW  = 61 * 61;     // 3721 output positions
constexpr int Kd   = 192;         // 3*8*8 reduction length
constexpr int BATCH = 16;
constexpr int XB   = 3 * 128 * 128;  // x batch stride
constexpr int XCC  = 128 * 128;      // x channel stride
constexpr int OSTR = 488 * 488;      // out batch stride
}

__global__ __launch_bounds__(256) void lc2d_kernel(
    const float* __restrict__ xg,   // [16][3][128][128]
    const float* __restrict__ wg,   // [61][61][64][3][8][8]
    const float* __restrict__ bg,   // [64][61][61]
    float* __restrict__ og)         // [16][488][488]
{
    __shared__ float xl[BATCH][Kd];   // 12 KB

    const int hw = blockIdx.x;
    const int h  = hw / 61;
    const int w  = hw - h * 61;
    const int t  = threadIdx.x;

    // ---- stage x patch: 1536 float2 loads (8B-aligned), [b][k] layout in LDS
    {
        const float* xbase = xg + (h * 2) * 128 + (w * 2);
        for (int f = t; f < 1536; f += 256) {
            const int b  = f / 96;          // 96 float2 per batch
            const int r  = f - b * 96;
            const int c  = r >> 5;          // 32 float2 per channel
            const int r2 = r & 31;
            const int i  = r2 >> 2;         // 4 float2 per row
            const int j0 = (r2 & 3) * 2;
            const float2 v = *reinterpret_cast<const float2*>(
                xbase + b * XB + c * XCC + i * 128 + j0);
            *reinterpret_cast<float2*>(&xl[b][c * 64 + i * 8 + j0]) = v;
        }
    }
    __syncthreads();

    const int lane = t & 63;
    const int wave = t >> 6;
    const int oc   = wave * 16 + (lane & 15);  // 64 output channels
    const int kh   = lane >> 4;                // K split 4-ways across lanes
    const int k0   = kh * 48;

    const float* wp = wg + (size_t)hw * (64 * Kd) + oc * Kd + k0;

    float acc[BATCH];
    #pragma unroll
    for (int b = 0; b < BATCH; ++b) acc[b] = 0.f;

    #pragma unroll
    for (int kk = 0; kk < 48; kk += 4) {
        const float4 wv = *reinterpret_cast<const float4*>(wp + kk);
        #pragma unroll
        for (int b = 0; b < BATCH; ++b) {
            const float4 xv = *reinterpret_cast<const float4*>(&xl[b][k0 + kk]);
            acc[b] = fmaf(wv.x, xv.x, acc[b]);
            acc[b] = fmaf(wv.y, xv.y, acc[b]);
            acc[b] = fmaf(wv.z, xv.z, acc[b]);
            acc[b] = fmaf(wv.w, xv.w, acc[b]);
        }
    }

    // ---- combine the 4 kh partials (lanes xor 16, xor 32)
    #pragma unroll
    for (int b = 0; b < BATCH; ++b) {
        acc[b] += __shfl_xor(acc[b], 16);
        acc[b] += __shfl_xor(acc[b], 32);
    }

    // ---- epilogue: bias + pixel-shuffle store; kh-groups split the batches
    const float bz   = bg[oc * NHW + hw];
    const int   orow = h * 8 + (oc >> 3);
    const int   ocol = w * 8 + (oc & 7);
    float* obase = og + orow * 488 + ocol;
    #pragma unroll
    for (int bb = 0; bb < 4; ++bb) {
        const int b = kh * 4 + bb;
        obase[(size_t)b * OSTR] = acc[b] + bz;
    }
}

extern "C" void kernel_launch(void* const* d_in, const int* in_sizes, int n_in,
                              void* d_out, int out_size, void* d_ws, size_t ws_size,
                              hipStream_t stream) {
    const float* x    = (const float*)d_in[0];
    const float* W    = (const float*)d_in[1];
    const float* bias = (const float*)d_in[2];
    float* out        = (float*)d_out;
    lc2d_kernel<<<dim3(NHW), dim3(256), 0, stream>>>(x, W, bias, out);
}

// Round 2
// 68.653 us; speedup vs baseline: 1.1156x; 1.1156x over previous
//
#include <hip/hip_runtime.h>

// LocallyConnected2d: x(16,3,128,128) f32, W(61,61,64,3,8,8) f32, bias(64,61,61) f32
// out(16,1,488,488) f32; stride 2, kernel 8, no pad; pixel-shuffle r=8 epilogue.
//
// R1: coalesced W via global_load_lds(16B) into 48 KB LDS (XOR-swizzled via
// pre-swizzled global source), x patch (12 KB) in LDS, 4oc x 4b register
// blocking per thread. Thread map: (q=lane&15 -> oc quad, kh=lane>>4 -> K/4
// slice, wave -> batch quad). __shfl_xor(16/32) combines K partials; thread
// kh stores batch wave*4+kh as one float4 across its oc quad.

namespace {
constexpr int NHW   = 61 * 61;
constexpr int Kd    = 192;          // 3*8*8
constexpr int OC    = 64;
constexpr int BATCH = 16;
constexpr int XB    = 3 * 128 * 128;
constexpr int XCC   = 128 * 128;
constexpr int OSTR  = 488 * 488;

__device__ __forceinline__ int swz(int oc) { return (oc ^ (oc >> 3)) & 7; }
}

__global__ __launch_bounds__(256, 2) void lc2d_kernel(
    const float* __restrict__ xg,   // [16][3][128][128]
    const float* __restrict__ wg,   // [61][61][64][3][8][8]
    const float* __restrict__ bg,   // [64][61][61]
    float* __restrict__ og)         // [16][488][488]
{
    __shared__ float4 wl[OC * 48];              // 48 KB, swizzled within rows
    __shared__ __align__(16) float xl[BATCH][Kd];  // 12 KB

    const int hw   = blockIdx.x;
    const int h    = hw / 61;
    const int w    = hw - h * 61;
    const int t    = threadIdx.x;
    const int lane = t & 63;
    const int wave = t >> 6;

    // ---- W staging: coalesced global -> linear LDS; source pre-swizzled so
    // LDS slot (oc, t4) holds element k4 = t4 ^ swz(oc).
    {
        const float* wbase = wg + (size_t)hw * (OC * Kd);
        #pragma unroll
        for (int ci = 0; ci < 12; ++ci) {
            const int s   = wave * 768 + ci * 64 + lane;   // float4 slot 0..3071
            const int ocs = s / 48;
            const int t4  = s - ocs * 48;
            const int k4  = t4 ^ swz(ocs);
            const float* src = wbase + (ocs * 48 + k4) * 4;
            __builtin_amdgcn_global_load_lds(
                (const __attribute__((address_space(1))) void*)src,
                (__attribute__((address_space(3))) void*)&wl[wave * 768 + ci * 64],
                16, 0, 0);
        }
    }

    // ---- x staging (manual float2, same mapping as R0 which validated)
    {
        const float* xbase = xg + (h * 2) * 128 + (w * 2);
        for (int f = t; f < 1536; f += 256) {
            const int b  = f / 96;
            const int r  = f - b * 96;
            const int c  = r >> 5;
            const int r2 = r & 31;
            const int i  = r2 >> 2;
            const int j0 = (r2 & 3) * 2;
            const float2 v = *reinterpret_cast<const float2*>(
                xbase + b * XB + c * XCC + i * 128 + j0);
            *reinterpret_cast<float2*>(&xl[b][c * 64 + i * 8 + j0]) = v;
        }
    }
    __syncthreads();

    const int q  = lane & 15;   // oc quad index
    const int kh = lane >> 4;   // K/4 slice

    // bias for my 4 ocs
    float bz[4];
    #pragma unroll
    for (int j = 0; j < 4; ++j) bz[j] = bg[(q * 4 + j) * NHW + hw];

    float acc[4][4];            // [j(oc)][bb(batch)]
    #pragma unroll
    for (int j = 0; j < 4; ++j)
        #pragma unroll
        for (int bb = 0; bb < 4; ++bb) acc[j][bb] = 0.f;

    const int kbase = kh * 12;  // float4 units within the K row

    #pragma unroll
    for (int kk = 0; kk < 12; ++kk) {
        float4 wv[4];
        #pragma unroll
        for (int j = 0; j < 4; ++j) {
            const int oc = q * 4 + j;
            wv[j] = wl[oc * 48 + ((kbase + kk) ^ swz(oc))];
        }
        #pragma unroll
        for (int bb = 0; bb < 4; ++bb) {
            const float4 xv = *reinterpret_cast<const float4*>(
                &xl[wave * 4 + bb][(kbase + kk) * 4]);
            #pragma unroll
            for (int j = 0; j < 4; ++j) {
                acc[j][bb] = fmaf(wv[j].x, xv.x, acc[j][bb]);
                acc[j][bb] = fmaf(wv[j].y, xv.y, acc[j][bb]);
                acc[j][bb] = fmaf(wv[j].z, xv.z, acc[j][bb]);
                acc[j][bb] = fmaf(wv[j].w, xv.w, acc[j][bb]);
            }
        }
    }

    // ---- combine the 4 kh partials (lanes xor 16, xor 32)
    #pragma unroll
    for (int j = 0; j < 4; ++j)
        #pragma unroll
        for (int bb = 0; bb < 4; ++bb) {
            acc[j][bb] += __shfl_xor(acc[j][bb], 16);
            acc[j][bb] += __shfl_xor(acc[j][bb], 32);
        }

    // ---- store: thread (q, kh, wave) stores batch b = wave*4+kh as float4
    // over its oc quad. oc = q*4+j -> row h*8 + (q>>1), col w*8 + (q&1)*4 + j.
    const int b    = wave * 4 + kh;
    const int orow = h * 8 + (q >> 1);
    const int ocol = w * 8 + (q & 1) * 4;
    float4 ov;
    ov.x = acc[0][kh] + bz[0];
    ov.y = acc[1][kh] + bz[1];
    ov.z = acc[2][kh] + bz[2];
    ov.w = acc[3][kh] + bz[3];
    *reinterpret_cast<float4*>(og + (size_t)b * OSTR + orow * 488 + ocol) = ov;
}

extern "C" void kernel_launch(void* const* d_in, const int* in_sizes, int n_in,
                              void* d_out, int out_size, void* d_ws, size_t ws_size,
                              hipStream_t stream) {
    const float* x    = (const float*)d_in[0];
    const float* W    = (const float*)d_in[1];
    const float* bias = (const float*)d_in[2];
    float* out        = (float*)d_out;
    lc2d_kernel<<<dim3(NHW), dim3(256), 0, stream>>>(x, W, bias, out);
}